// Round 10
// baseline (236.982 us; speedup 1.0000x reference)
//
#include <hip/hip_runtime.h>

// Conv2Central: reference = stencil applied 4x (batch flips are on the batch
// axis and commute with the per-slice 2D stencil, so they cancel).
// Composed separable 5-tap filter: (1+0.5z)^4 = {1, 2, 1.5, 0.5, 0.0625}.
//
// Round 9: pure-TLP register-streaming version. No LDS, no barriers.
// Each thread owns a 4-wide column strip and streams 16 output rows with a
// 4-deep sliding window of row-filtered values in registers. Latency is
// hidden by 32 waves/CU (8 blocks/CU at <=64 VGPR, LDS=0), keeping the VMEM
// pipe continuously busy instead of the burst-drain-compute cycle of the
// LDS version (which idled memory ~half the time at 2.9 TB/s).

#define N_IMG 32
#define H_IMG 1024
#define W_IMG 1024
#define BAND  16   // output rows per block

__device__ __forceinline__ float4 rowfilt4(float4 a, float4 b) {
    const float c1 = 2.0f, c2 = 1.5f, c3 = 0.5f, c4 = 0.0625f;  // c0 = 1
    float4 t;
    t.x = a.x + c1*a.y + c2*a.z + c3*a.w + c4*b.x;
    t.y = a.y + c1*a.z + c2*a.w + c3*b.x + c4*b.y;
    t.z = a.z + c1*a.w + c2*b.x + c3*b.y + c4*b.z;
    t.w = a.w + c1*b.x + c2*b.y + c3*b.z + c4*b.w;
    return t;
}

__global__ __launch_bounds__(256) void stencil4_stream(const float* __restrict__ in,
                                                       float* __restrict__ out) {
    const float c1 = 2.0f, c2 = 1.5f, c3 = 0.5f, c4 = 0.0625f;  // c0 = 1

    const int tid = threadIdx.x;
    const int j0  = tid * 4;                 // 256 threads * 4 cols = 1024
    const int i0  = blockIdx.x * BAND;       // row band
    const int n   = blockIdx.y;

    const float* img = in  + (size_t)n * H_IMG * W_IMG + j0;
    float*       o   = out + (size_t)n * H_IMG * W_IMG + j0;
    const bool hasR  = (j0 + 4 < W_IMG);     // only lane 255 lacks a right nbr

    // row-filter input row r (global index), zero-padded on the right
    auto rf = [&](int r) -> float4 {
        const float* p = img + (size_t)r * W_IMG;
        float4 a = *reinterpret_cast<const float4*>(p);
        float4 b = hasR ? *reinterpret_cast<const float4*>(p + 4)
                        : make_float4(0.f, 0.f, 0.f, 0.f);
        return rowfilt4(a, b);
    };

    // Prologue: rows i0..i0+3 (always < H since i0 <= H-BAND).
    float4 w0 = rf(i0 + 0);
    float4 w1 = rf(i0 + 1);
    float4 w2 = rf(i0 + 2);
    float4 w3 = rf(i0 + 3);

    #pragma unroll 4
    for (int r = 0; r < BAND; ++r) {
        const int gi = i0 + r + 4;           // input row feeding this output
        float4 t = (gi < H_IMG) ? rf(gi)     // block-uniform guard (last band)
                                : make_float4(0.f, 0.f, 0.f, 0.f);
        float4 y;
        y.x = w0.x + c1*w1.x + c2*w2.x + c3*w3.x + c4*t.x;
        y.y = w0.y + c1*w1.y + c2*w2.y + c3*w3.y + c4*t.y;
        y.z = w0.z + c1*w1.z + c2*w2.z + c3*w3.z + c4*t.z;
        y.w = w0.w + c1*w1.w + c2*w2.w + c3*w3.w + c4*t.w;
        *reinterpret_cast<float4*>(o + (size_t)(i0 + r) * W_IMG) = y;
        w0 = w1; w1 = w2; w2 = w3; w3 = t;
    }
}

extern "C" void kernel_launch(void* const* d_in, const int* in_sizes, int n_in,
                              void* d_out, int out_size, void* d_ws, size_t ws_size,
                              hipStream_t stream) {
    const float* img = (const float*)d_in[0];
    float*       out = (float*)d_out;

    dim3 grid(H_IMG / BAND, N_IMG);   // 64 x 32 = 2048 blocks -> 8 blocks/CU
    dim3 block(256);
    stencil4_stream<<<grid, block, 0, stream>>>(img, out);
}